// Round 1
// baseline (306.239 us; speedup 1.0000x reference)
//
#include <hip/hip_runtime.h>
#include <math.h>

#define TDIM 1000
#define BDIM 32
#define VDIM 1000
#define UDIM 100
#define SDIM 201            // 2*U+1
#define EROW 104            // padded emission-row stride (101 used)
#define NEG_EPS -69.07755278982137f   // log(1e-30), the reference's "zero"

// ---------------------------------------------------------------------------
// Phase 1: per (t,b) row, compute log_softmax normalizer over V and gather
// the 101 emissions actually used by the recursion:
//   etab[b][t][u]   = log_softmax(lp[t,b,:])[targets[b,u]]   u in [0,100)
//   etab[b][t][100] = log_softmax(lp[t,b,:])[BLANK=0]
// ---------------------------------------------------------------------------
__global__ __launch_bounds__(256) void k_lsm_gather(
    const float* __restrict__ lp, const int* __restrict__ targets,
    float* __restrict__ etab)
{
    const int row = blockIdx.x;            // row = t*B + b
    const int t = row / BDIM;
    const int b = row - t * BDIM;
    const float* base = lp + (size_t)row * VDIM;
    const int tid = threadIdx.x;

    float v[4];
    float m = -INFINITY;
#pragma unroll
    for (int i = 0; i < 4; ++i) {
        int idx = tid + i * 256;
        v[i] = (idx < VDIM) ? base[idx] : -INFINITY;
        m = fmaxf(m, v[i]);
    }
#pragma unroll
    for (int off = 32; off >= 1; off >>= 1)
        m = fmaxf(m, __shfl_xor(m, off));   // wave64 reduce

    __shared__ float redm[4], reds[4];
    const int wave = tid >> 6, lane = tid & 63;
    if (lane == 0) redm[wave] = m;
    __syncthreads();
    m = fmaxf(fmaxf(redm[0], redm[1]), fmaxf(redm[2], redm[3]));

    float ssum = 0.f;
#pragma unroll
    for (int i = 0; i < 4; ++i) {
        int idx = tid + i * 256;
        if (idx < VDIM) ssum += __expf(v[i] - m);
    }
#pragma unroll
    for (int off = 32; off >= 1; off >>= 1)
        ssum += __shfl_xor(ssum, off);
    if (lane == 0) reds[wave] = ssum;
    __syncthreads();
    const float denom = m + __logf(reds[0] + reds[1] + reds[2] + reds[3]);

    // gather (row is L1-resident: we just streamed all 4 KB of it)
    if (tid <= UDIM) {
        const int c = (tid < UDIM) ? targets[b * UDIM + tid] : 0; // 100 -> blank
        etab[((size_t)b * TDIM + t) * EROW + tid] = base[c] - denom;
    }
}

// ---------------------------------------------------------------------------
// Phase 2: alpha recursion. One block per batch element, thread s = state.
// Double-buffered alpha in LDS, 1 barrier per timestep, emission prefetch.
// ---------------------------------------------------------------------------
__global__ __launch_bounds__(256) void k_alpha(
    const float* __restrict__ etab, const int* __restrict__ targets,
    const int* __restrict__ ilen, const int* __restrict__ tlen,
    float* __restrict__ out)
{
    const int b = blockIdx.x;
    const int s = threadIdx.x;
    __shared__ float alpha[2][260];

    const bool valid = (s < SDIM);
    const int u = s >> 1;
    const int eoff = (s & 1) ? u : UDIM;   // odd: label u, even: blank slot
    bool allow = false;                    // skip transition alpha[s-2]
    if (valid && (s & 1) && s >= 3)
        allow = targets[b * UDIM + u] != targets[b * UDIM + u - 1];

    const float* eb = etab + (size_t)b * TDIM * EROW;

    // t = 0 init: alpha[0]=x[0,blank], alpha[1]=x[0,targets[0]], else log(1e-30)
    const float e0 = valid ? eb[eoff] : NEG_EPS;
    alpha[0][s] = (valid && s < 2) ? e0 : NEG_EPS;
    __syncthreads();

    int L = ilen[b];
    if (L > TDIM) L = TDIM;   // updates applied only while t < input_length

    int cur = 0;
    float e_next = (L > 1 && valid) ? eb[(size_t)EROW + eoff] : 0.f;
    for (int t = 1; t < L; ++t) {
        const float e = e_next;
        if (t + 1 < L && valid)
            e_next = eb[(size_t)(t + 1) * EROW + eoff];   // prefetch next step

        const float a0 = alpha[cur][s];
        const float a1 = (s >= 1) ? alpha[cur][s - 1] : -INFINITY;
        const float a2 = allow ? alpha[cur][s - 2] : -INFINITY;
        const float mx = fmaxf(a0, fmaxf(a1, a2));
        const float nv = mx + __logf(__expf(a0 - mx) + __expf(a1 - mx) +
                                     __expf(a2 - mx)) + e;
        alpha[cur ^ 1][s] = valid ? nv : NEG_EPS;
        __syncthreads();
        cur ^= 1;
    }

    if (s == 0) {
        const int ul = tlen[b];
        const float x1 = alpha[cur][2 * ul - 1];
        const float x2 = alpha[cur][2 * ul];
        const float mx = fmaxf(x1, x2);
        out[b] = -(mx + __logf(__expf(x1 - mx) + __expf(x2 - mx)));
    }
}

extern "C" void kernel_launch(void* const* d_in, const int* in_sizes, int n_in,
                              void* d_out, int out_size, void* d_ws, size_t ws_size,
                              hipStream_t stream) {
    const float* lp      = (const float*)d_in[0];   // [T,B,V] f32
    const int*   targets = (const int*)d_in[1];     // [B,U] i32
    const int*   ilen    = (const int*)d_in[2];     // [B] i32
    const int*   tlen    = (const int*)d_in[3];     // [B] i32
    float* out  = (float*)d_out;                    // [B] f32
    float* etab = (float*)d_ws;                     // B*T*EROW*4 = 13.3 MB

    k_lsm_gather<<<TDIM * BDIM, 256, 0, stream>>>(lp, targets, etab);
    k_alpha<<<BDIM, 256, 0, stream>>>(etab, targets, ilen, tlen, out);
}

// Round 2
// 236.995 us; speedup vs baseline: 1.2922x; 1.2922x over previous
//
#include <hip/hip_runtime.h>
#include <math.h>

#define TDIM 1000
#define BDIM 32
#define VDIM 1000
#define UDIM 100
#define SDIM 201              // 2*U+1
#define EROW 104              // padded emission-row stride (102 used)
#define LOG2E 1.4426950408889634f
#define LN2   0.6931471805599453f
#define NEG_EPS2 -99.65784284662087f   // log2(1e-30), reference's "zero" in log2 domain

// ---------------------------------------------------------------------------
// Phase 1: one wave per (t,b) row. float4-stream the 1000 classes, wave-reduce
// max and sum(exp), then gather the 101 used emissions in LOG2 domain:
//   etab[b][t][u]   = (lp[t,b,targets[b,u]] - denom) * log2e    u in [0,100)
//   etab[b][t][100] = (lp[t,b,BLANK] - denom) * log2e
// ---------------------------------------------------------------------------
__global__ __launch_bounds__(256) void k_lsm_gather(
    const float* __restrict__ lp, const int* __restrict__ targets,
    float* __restrict__ etab)
{
    const int w = threadIdx.x >> 6, l = threadIdx.x & 63;
    const int row = blockIdx.x * 4 + w;        // row = t*B + b
    const int t = row / BDIM;
    const int b = row - t * BDIM;
    const float* base = lp + (size_t)row * VDIM;
    const float4* p4 = (const float4*)base;    // 250 float4 per row

    float4 v0 = p4[l];
    float4 v1 = p4[64 + l];
    float4 v2 = p4[128 + l];
    float4 v3;
    if (l < 58) v3 = p4[192 + l];
    else        v3 = make_float4(-INFINITY, -INFINITY, -INFINITY, -INFINITY);

    float m = fmaxf(fmaxf(fmaxf(v0.x, v0.y), fmaxf(v0.z, v0.w)),
                    fmaxf(fmaxf(v1.x, v1.y), fmaxf(v1.z, v1.w)));
    m = fmaxf(m, fmaxf(fmaxf(v2.x, v2.y), fmaxf(v2.z, v2.w)));
    m = fmaxf(m, fmaxf(fmaxf(v3.x, v3.y), fmaxf(v3.z, v3.w)));
#pragma unroll
    for (int off = 32; off >= 1; off >>= 1)
        m = fmaxf(m, __shfl_xor(m, off));

    float s = __expf(v0.x - m) + __expf(v0.y - m) + __expf(v0.z - m) + __expf(v0.w - m)
            + __expf(v1.x - m) + __expf(v1.y - m) + __expf(v1.z - m) + __expf(v1.w - m)
            + __expf(v2.x - m) + __expf(v2.y - m) + __expf(v2.z - m) + __expf(v2.w - m)
            + __expf(v3.x - m) + __expf(v3.y - m) + __expf(v3.z - m) + __expf(v3.w - m);
#pragma unroll
    for (int off = 32; off >= 1; off >>= 1)
        s += __shfl_xor(s, off);

    const float denom = m + __logf(s);
    float* erow = etab + (size_t)(b * TDIM + t) * EROW;
    if (l < 50) {
        const int c0 = targets[b * UDIM + 2 * l];
        const int c1 = targets[b * UDIM + 2 * l + 1];
        float2 o;
        o.x = (base[c0] - denom) * LOG2E;
        o.y = (base[c1] - denom) * LOG2E;
        *(float2*)(erow + 2 * l) = o;
    } else if (l == 50) {
        erow[100] = (base[0] - denom) * LOG2E;   // blank
    }
}

// ---------------------------------------------------------------------------
// Phase 2: one wave per batch element. Lane l owns states s = 4l..4l+3
// (even=blank, odd=labels 2l, 2l+1). Only cross-lane dependency per step is
// the left neighbor's a3 -> one __shfl_up, no LDS, no barriers.
// Emission loads software-pipelined 4 deep. All math in log2 domain.
// ---------------------------------------------------------------------------
__global__ __launch_bounds__(64) void k_alpha(
    const float* __restrict__ etab, const int* __restrict__ targets,
    const int* __restrict__ ilen, const int* __restrict__ tlen,
    float* __restrict__ out)
{
    const int b = blockIdx.x;
    const int l = threadIdx.x;                 // 0..63
    const float* eb = etab + (size_t)b * TDIM * EROW;
    const int eoff = (2 * l <= 100) ? 2 * l : 100;   // clamp idle lanes in-row

    bool allow1 = false, allow3 = false;       // skip-transitions for s=4l+1, 4l+3
    if (l < 50) {
        const int c0 = targets[b * UDIM + 2 * l];
        const int c1 = targets[b * UDIM + 2 * l + 1];
        allow3 = (c1 != c0);
        if (l >= 1) allow1 = (c0 != targets[b * UDIM + 2 * l - 1]);
    }

    // t = 0 init
    float2 lab0 = *(const float2*)(eb + eoff);
    float bl0 = eb[100];
    float a0 = (l == 0) ? bl0 : NEG_EPS2;      // s=0: blank emission
    float a1 = (l == 0) ? lab0.x : NEG_EPS2;   // s=1: first label
    float a2 = NEG_EPS2, a3 = NEG_EPS2;

    int L = ilen[b];
    if (L > TDIM) L = TDIM;

#define STEP(LAB_, BL_) {                                                        \
    float pA3 = __shfl_up(a3, 1);                                                \
    if (l == 0) pA3 = -INFINITY;                                                 \
    const float m0 = fmaxf(a0, pA3);                                             \
    const float n0 = m0 + __builtin_amdgcn_logf(                                 \
        1.f + __builtin_amdgcn_exp2f(fminf(a0, pA3) - m0)) + (BL_);              \
    const float s1 = allow1 ? pA3 : -INFINITY;                                   \
    const float m1 = fmaxf(a1, fmaxf(a0, s1));                                   \
    const float n1 = m1 + __builtin_amdgcn_logf(                                 \
        __builtin_amdgcn_exp2f(a1 - m1) + __builtin_amdgcn_exp2f(a0 - m1) +      \
        __builtin_amdgcn_exp2f(s1 - m1)) + (LAB_).x;                             \
    const float m2 = fmaxf(a2, a1);                                              \
    const float n2 = m2 + __builtin_amdgcn_logf(                                 \
        1.f + __builtin_amdgcn_exp2f(fminf(a2, a1) - m2)) + (BL_);               \
    const float s3 = allow3 ? a1 : -INFINITY;                                    \
    const float m3 = fmaxf(a3, fmaxf(a2, s3));                                   \
    const float n3 = m3 + __builtin_amdgcn_logf(                                 \
        __builtin_amdgcn_exp2f(a3 - m3) + __builtin_amdgcn_exp2f(a2 - m3) +      \
        __builtin_amdgcn_exp2f(s3 - m3)) + (LAB_).y;                             \
    a0 = n0; a1 = n1; a2 = n2; a3 = n3; }

    // 4-deep software pipeline over t
    float2 lab[4]; float bl[4];
#pragma unroll
    for (int j = 0; j < 4; ++j) {
        int tj = 1 + j; if (tj > TDIM - 1) tj = TDIM - 1;
        lab[j] = *(const float2*)(eb + (size_t)tj * EROW + eoff);
        bl[j]  = eb[(size_t)tj * EROW + 100];
    }
    int t = 1;
    for (; t + 3 < L; t += 4) {
#pragma unroll
        for (int j = 0; j < 4; ++j) {
            STEP(lab[j], bl[j]);
            int tn = t + j + 4; if (tn > TDIM - 1) tn = TDIM - 1;   // always safe
            lab[j] = *(const float2*)(eb + (size_t)tn * EROW + eoff);
            bl[j]  = eb[(size_t)tn * EROW + 100];
        }
    }
    for (; t < L; ++t) {   // tail (<4 iters), direct loads
        float2 lb = *(const float2*)(eb + (size_t)t * EROW + eoff);
        float bb = eb[(size_t)t * EROW + 100];
        STEP(lb, bb);
    }
#undef STEP

    // gather final alphas, lane 0 computes the loss
    __shared__ float A[256];
    A[4 * l + 0] = a0; A[4 * l + 1] = a1; A[4 * l + 2] = a2; A[4 * l + 3] = a3;
    __syncthreads();
    if (l == 0) {
        const int u = tlen[b];
        const float x1 = A[2 * u - 1], x2 = A[2 * u];
        const float mx = fmaxf(x1, x2), mn = fminf(x1, x2);
        const float lse2 = mx + __builtin_amdgcn_logf(
            1.f + __builtin_amdgcn_exp2f(mn - mx));
        out[b] = -(LN2 * lse2);
    }
}

extern "C" void kernel_launch(void* const* d_in, const int* in_sizes, int n_in,
                              void* d_out, int out_size, void* d_ws, size_t ws_size,
                              hipStream_t stream) {
    const float* lp      = (const float*)d_in[0];   // [T,B,V] f32
    const int*   targets = (const int*)d_in[1];     // [B,U] i32
    const int*   ilen    = (const int*)d_in[2];     // [B] i32
    const int*   tlen    = (const int*)d_in[3];     // [B] i32
    float* out  = (float*)d_out;                    // [B] f32
    float* etab = (float*)d_ws;                     // B*T*EROW*4 = 13.3 MB

    k_lsm_gather<<<TDIM * BDIM / 4, 256, 0, stream>>>(lp, targets, etab);
    k_alpha<<<BDIM, 64, 0, stream>>>(etab, targets, ilen, tlen, out);
}